// Round 6
// baseline (182.117 us; speedup 1.0000x reference)
//
#include <hip/hip_runtime.h>
#include <stdint.h>

#define NSITE 512
#define DD    64
#define NB    64
#define NO    10
#define NSEG  16
#define SEGLEN 32
#define SLAB_BYTES 32768   // fp32 site slab stride
#define PACK_BYTES 16384   // packed bf16 Wstk image (front half of slab)

typedef short bf16x8 __attribute__((ext_vector_type(8)));
typedef float f32x16 __attribute__((ext_vector_type(16)));

// trunc-pack two f32 -> packed bf16 dword (lo=a, hi=b) in ONE v_perm_b32
__device__ __forceinline__ uint32_t pk2(float a, float b) {
    return __builtin_amdgcn_perm(__float_as_uint(b), __float_as_uint(a), 0x07060302);
}

// ---------------------------------------------------------------------------
// Pack W fp32 [s][l][r][w] -> bf16 K-stacked A-operand image, IN PLACE (front
// 16 KB of each 32 KB slab).  A[m][kap=2k+w] = left: W_w[k][m] (transpose),
// right: W_w[m][k].  Image layout: dword od = chunk*256 + H*128 + m5*4 + d,
// chunk = (m>>5)*8 + (kap>>4), H = (kap>>3)&1, m5 = m&31, d = ((kap&7)>>1);
// dword = {bf(w=0), bf(w=1)} at k = 8*(chunk&7) + 4H + d.  A-frag read in
// stage1 is then *(uint4*)(ring + chunk*1024 + lane*16): lane-contiguous,
// bank-conflict-free, and global_load_lds copies the image verbatim.
// ---------------------------------------------------------------------------
__global__ __launch_bounds__(256) void pack_kernel(float* __restrict__ wl,
                                                   float* __restrict__ wr) {
    const int g = blockIdx.x;                 // 0..1023
    const int right = (g >= NSITE) ? 1 : 0;
    const int s = right ? g - NSITE : g;
    float* base = (right ? wr : wl) + (size_t)s * (SLAB_BYTES / 4);

    __shared__ float2 st[DD * 65];            // padded [l][r] (w0,w1) pairs
    const float4* src4 = (const float4*)base; // 16B/lane loads (was 8B)
    for (int e4 = threadIdx.x; e4 < DD * DD / 2; e4 += 256) {
        const float4 v = src4[e4];
        const int e = e4 * 2;                 // e even -> same padded row for e, e+1
        float2* d = &st[(e >> 6) * 65 + (e & 63)];
        d[0] = make_float2(v.x, v.y);
        d[1] = make_float2(v.z, v.w);
    }
    __syncthreads();

    uint32_t* out = (uint32_t*)base;          // front 16 KB = 4096 dwords
    #pragma unroll
    for (int rr = 0; rr < 16; ++rr) {
        const int od = rr * 256 + threadIdx.x;        // coalesced writes
        const int chunk = od >> 8, i = chunk >> 3, sk = chunk & 7;
        const int H = (od >> 7) & 1, m5 = (od >> 2) & 31, d = od & 3;
        const int m = 32 * i + m5, k = 8 * sk + 4 * H + d;
        const float2 a = right ? st[m * 65 + k] : st[k * 65 + m];
        out[od] = pk2(a.x, a.y);              // lo = w0, hi = w1
    }
}

__device__ __forceinline__ void dma16(const void* gp, void* lp) {
    __builtin_amdgcn_global_load_lds(
        (const __attribute__((address_space(1))) uint32_t*)gp,
        (__attribute__((address_space(3))) uint32_t*)lp, 16, 0, 0);
}

// ---------------------------------------------------------------------------
// Stage 1: per (side, segment-of-32, batch) build the 64x64 segment product
// via MFMA with K=128 per site (x-combine folded into the contraction).
// 512 blocks x 4 waves (2 blocks/CU); wave = one batch; 4-slot shared DMA
// ring, prefetch depth 2, vmcnt(8)+s_barrier (round-3-proven cadence).
// T stays ENTIRELY in registers: B-frag for kap-step s = own-lane acc regs
// 4(s&3)..+3 of quadrant [s>>2][cj], scaled {x0,x1} and perm-packed.
// s_setprio(1) around the compute phase (T5) -- the co-resident block's
// waves are independently phased, so prioritizing the MFMA/pack phase over
// the other block's DMA-issue phase can pay.
// ---------------------------------------------------------------------------
__global__ __launch_bounds__(256, 2) void stage1_kernel(
        const float* __restrict__ x, float* __restrict__ wl, float* __restrict__ wr) {
    const int bid  = blockIdx.x;          // 0..511
    const int side = bid >> 8;
    const int seg  = (bid >> 4) & 15;
    const int bq   = bid & 15;
    const int wave = threadIdx.x >> 6;
    const int lane = threadIdx.x & 63;
    const int b    = bq * 4 + wave;
    const int m5   = lane & 31;
    const int H    = lane >> 5;

    __shared__ __align__(16) char ring[4][PACK_BYTES];   // 64 KB
    __shared__ float2 xs[4][SEGLEN];

    char* wbuf = (char*)(side ? wr : wl);

    if (lane < SEGLEN) {
        const float2* xp = ((const float2*)x) + (size_t)b * 1024 + (side ? NSITE : 0);
        const int sg = seg * SEGLEN + (side ? SEGLEN - 1 - lane : lane);
        xs[wave][lane] = xp[sg];
    }

    auto siteAddr = [&](int t) -> const char* {
        const int sg = seg * SEGLEN + (side ? SEGLEN - 1 - t : t);
        return wbuf + (size_t)sg * SLAB_BYTES;
    };

    #pragma unroll
    for (int t0 = 0; t0 < 2; ++t0) {
        const char* sb = siteAddr(t0);
        #pragma unroll
        for (int c = 0; c < 4; ++c) {
            const int ch = wave * 4 + c;
            dma16(sb + ch * 1024 + lane * 16, ring[t0] + ch * 1024);
        }
    }

    // acc := Identity (C/D layout: row=(q&3)+8(q>>2)+4H, col=32j+m5)
    f32x16 acc[2][2];
    #pragma unroll
    for (int i = 0; i < 2; ++i)
        #pragma unroll
        for (int j = 0; j < 2; ++j)
            #pragma unroll
            for (int q = 0; q < 16; ++q) {
                const int row = (q & 3) + 8 * (q >> 2) + 4 * H;
                acc[i][j][q] = (i == j && row == m5) ? 1.f : 0.f;
            }

    for (int t = 0; t < SEGLEN; ++t) {
        int t2 = t + 2; if (t2 > SEGLEN - 1) t2 = SEGLEN - 1;   // clamped dummy keeps cadence
        {
            const char* sb = siteAddr(t2);
            char* lb = ring[(t + 2) & 3];
            #pragma unroll
            for (int c = 0; c < 4; ++c) {
                const int ch = wave * 4 + c;
                dma16(sb + ch * 1024 + lane * 16, lb + ch * 1024);
            }
        }
        asm volatile("s_waitcnt vmcnt(8)" ::: "memory");
        asm volatile("s_barrier" ::: "memory");

        const char* rb = ring[t & 3];
        uint4 af[2][8];
        #pragma unroll
        for (int i = 0; i < 2; ++i)
            #pragma unroll
            for (int sk = 0; sk < 8; ++sk)
                af[i][sk] = *(const uint4*)(rb + (i * 8 + sk) * 1024 + lane * 16);

        const float2 xv = xs[wave][t];
        f32x16 nacc[2][2] = {};
        __builtin_amdgcn_s_setprio(1);
        #pragma unroll
        for (int sk = 0; sk < 8; ++sk) {
            const int mi = sk >> 2, qb = 4 * (sk & 3);
            union { bf16x8 v; uint32_t u[4]; } bf[2];
            #pragma unroll
            for (int j = 0; j < 2; ++j)
                #pragma unroll
                for (int dlt = 0; dlt < 4; ++dlt) {
                    const float v = acc[mi][j][qb + dlt];
                    bf[j].u[dlt] = pk2(xv.x * v, xv.y * v);   // kap even: x0, odd: x1
                }
            #pragma unroll
            for (int i = 0; i < 2; ++i) {
                union { bf16x8 v; uint4 u; } a; a.u = af[i][sk];
                #pragma unroll
                for (int j = 0; j < 2; ++j)
                    nacc[i][j] = __builtin_amdgcn_mfma_f32_32x32x16_bf16(
                        a.v, bf[j].v, nacc[i][j], 0, 0, 0);
            }
        }
        __builtin_amdgcn_s_setprio(0);
        #pragma unroll
        for (int i = 0; i < 2; ++i)
            #pragma unroll
            for (int j = 0; j < 2; ++j)
                acc[i][j] = nacc[i][j];
    }

    // write P (final T, bf16, uint16 index c*64+r) into slab back-halves
    {
        const int p = b * NSEG + seg;                    // 0..1023 per side
        char* pdst = wbuf + (size_t)(p >> 1) * SLAB_BYTES + PACK_BYTES + (p & 1) * 8192;
        #pragma unroll
        for (int i = 0; i < 2; ++i)
            #pragma unroll
            for (int j = 0; j < 2; ++j) {
                const int c = 32 * j + m5;
                #pragma unroll
                for (int Q = 0; Q < 4; ++Q) {
                    const int r0 = 32 * i + 8 * Q + 4 * H;
                    uint2 val;
                    val.x = pk2(acc[i][j][4 * Q + 0], acc[i][j][4 * Q + 1]);
                    val.y = pk2(acc[i][j][4 * Q + 2], acc[i][j][4 * Q + 3]);
                    *(uint2*)(pdst + c * 128 + r0 * 2) = val;
                }
            }
    }
    asm volatile("s_waitcnt vmcnt(0)" ::: "memory");   // drain DMA before endpgm
}

// ---------------------------------------------------------------------------
// Stage 2: fold 16 segment matrices into the boundary vector per chain.
// 128 blocks x 256 threads; 4 waves split the c-sum, LDS tree reduce.
// Register prefetch of next segment's P + raw s_barrier with manual
// lgkmcnt(0) only (no vmcnt drain) so the prefetch loads stay in flight
// across BOTH barriers; they are waited only at the pv<-nv copy.
// ---------------------------------------------------------------------------
__global__ __launch_bounds__(256) void stage2_kernel(
        const float* __restrict__ wl, const float* __restrict__ wr,
        float* __restrict__ vbuf) {
    const int chain = blockIdx.x;        // 0..127
    const int side  = chain >> 6, b = chain & 63;
    const int tid   = threadIdx.x, r = tid & 63, cg = tid >> 6;
    const char* wbuf = (const char*)(side ? wr : wl);

    __shared__ float vsh[DD];
    __shared__ float part[4][DD];
    if (tid < DD) vsh[tid] = (tid == 0) ? 1.f : 0.f;

    auto Pseg = [&](int gi) -> const uint16_t* {
        const int g = side ? (NSEG - 1 - gi) : gi;
        const int p = b * NSEG + g;
        return (const uint16_t*)(wbuf
            + (size_t)(p >> 1) * SLAB_BYTES + PACK_BYTES + (p & 1) * 8192);
    };

    float pv[16];
    {
        const uint16_t* P = Pseg(0);
        #pragma unroll
        for (int cc = 0; cc < 16; ++cc)
            pv[cc] = __uint_as_float(((uint32_t)P[(cg * 16 + cc) * 64 + r]) << 16);
    }
    __syncthreads();

    for (int gi = 0; gi < NSEG; ++gi) {
        float nv[16];
        const bool more = (gi + 1 < NSEG);
        if (more) {
            const uint16_t* Pn = Pseg(gi + 1);          // issue early; waited at copy
            #pragma unroll
            for (int cc = 0; cc < 16; ++cc)
                nv[cc] = __uint_as_float(((uint32_t)Pn[(cg * 16 + cc) * 64 + r]) << 16);
        }
        float acc = 0.f;
        #pragma unroll
        for (int cc = 0; cc < 16; ++cc)
            acc = fmaf(vsh[cg * 16 + cc], pv[cc], acc);
        part[cg][r] = acc;
        asm volatile("s_waitcnt lgkmcnt(0)" ::: "memory");
        __builtin_amdgcn_s_barrier();
        if (tid < DD) vsh[tid] = part[0][tid] + part[1][tid] + part[2][tid] + part[3][tid];
        asm volatile("s_waitcnt lgkmcnt(0)" ::: "memory");
        __builtin_amdgcn_s_barrier();
        if (more) {
            #pragma unroll
            for (int cc = 0; cc < 16; ++cc) pv[cc] = nv[cc];
        }
    }
    if (tid < DD) vbuf[chain * DD + tid] = vsh[tid];
}

// out[b,o] = sum_{l,r} vL[b,l] * core[o,l,r] * wR[b,r]
__global__ __launch_bounds__(64) void finalize_kernel(
        const float* __restrict__ core,
        const float* __restrict__ vbuf,
        float* __restrict__ out) {
    const int b    = blockIdx.x;
    const int lane = threadIdx.x;
    __shared__ float vls[DD];
    vls[lane] = vbuf[b * DD + lane];
    const float wr = vbuf[(NB + b) * DD + lane];
    __syncthreads();
    for (int o = 0; o < NO; ++o) {
        float acc = 0.f;
        #pragma unroll 8
        for (int l = 0; l < DD; ++l)
            acc += vls[l] * core[(o * DD + l) * DD + lane];
        acc *= wr;
        #pragma unroll
        for (int off = 32; off > 0; off >>= 1)
            acc += __shfl_xor(acc, off, 64);
        if (lane == 0) out[b * NO + o] = acc;
    }
}

extern "C" void kernel_launch(void* const* d_in, const int* in_sizes, int n_in,
                              void* d_out, int out_size, void* d_ws, size_t ws_size,
                              hipStream_t stream) {
    const float* x    = (const float*)d_in[0];   // [64][1024][2]
    float*       wl   = (float*)d_in[1];         // [512][64][64][2] -> packed + P scratch
    const float* core = (const float*)d_in[2];   // [10][64][64]
    float*       wr   = (float*)d_in[3];         // [512][64][64][2] -> packed + P scratch
    float* vbuf = (float*)d_ws;                  // 32 KB

    pack_kernel<<<2 * NSITE, 256, 0, stream>>>(wl, wr);
    stage1_kernel<<<512, 256, 0, stream>>>(x, wl, wr);
    stage2_kernel<<<2 * NB, 256, 0, stream>>>(wl, wr, vbuf);
    finalize_kernel<<<NB, DD, 0, stream>>>(core, vbuf, (float*)d_out);
}

// Round 8
// 180.998 us; speedup vs baseline: 1.0062x; 1.0062x over previous
//
#include <hip/hip_runtime.h>
#include <stdint.h>

#define NSITE 512
#define DD    64
#define NB    64
#define NO    10
#define NSEG  16
#define SEGLEN 32
#define SLAB_BYTES 32768   // fp32 site slab stride
#define PACK_BYTES 16384   // packed bf16 Wstk image (front half of slab)

typedef short bf16x8 __attribute__((ext_vector_type(8)));
typedef float f32x16 __attribute__((ext_vector_type(16)));

// trunc-pack two f32 -> packed bf16 dword (lo=a, hi=b) in ONE v_perm_b32
__device__ __forceinline__ uint32_t pk2(float a, float b) {
    return __builtin_amdgcn_perm(__float_as_uint(b), __float_as_uint(a), 0x07060302);
}

// packed f32 pair multiply: {a.x*b.x, a.y*b.y} in one VOP3P instruction
__device__ __forceinline__ float2 pkmul2(float2 a, float2 b) {
    float2 r;
    asm("v_pk_mul_f32 %0, %1, %2" : "=v"(r) : "v"(a), "v"(b));
    return r;
}

// ---------------------------------------------------------------------------
// Pack W fp32 [s][l][r][w] -> bf16 K-stacked A-operand image, IN PLACE (front
// 16 KB of each 32 KB slab).  A[m][kap=2k+w] = left: W_w[k][m] (transpose),
// right: W_w[m][k].  Image layout: dword od = chunk*256 + H*128 + m5*4 + d,
// chunk = (m>>5)*8 + (kap>>4), H = (kap>>3)&1, m5 = m&31, d = ((kap&7)>>1);
// dword = {bf(w=0), bf(w=1)} at k = 8*(chunk&7) + 4H + d.  A-frag read in
// stage1 is then *(uint4*)(ring + chunk*1024 + lane*16): lane-contiguous,
// bank-conflict-free, and global_load_lds copies the image verbatim.
// ---------------------------------------------------------------------------
__global__ __launch_bounds__(256) void pack_kernel(float* __restrict__ wl,
                                                   float* __restrict__ wr) {
    const int g = blockIdx.x;                 // 0..1023
    const int right = (g >= NSITE) ? 1 : 0;
    const int s = right ? g - NSITE : g;
    float* base = (right ? wr : wl) + (size_t)s * (SLAB_BYTES / 4);

    __shared__ float2 st[DD * 65];            // padded [l][r] (w0,w1) pairs
    const float4* src4 = (const float4*)base; // 16B/lane loads
    for (int e4 = threadIdx.x; e4 < DD * DD / 2; e4 += 256) {
        const float4 v = src4[e4];
        const int e = e4 * 2;                 // e even -> same padded row for e, e+1
        float2* d = &st[(e >> 6) * 65 + (e & 63)];
        d[0] = make_float2(v.x, v.y);
        d[1] = make_float2(v.z, v.w);
    }
    __syncthreads();

    uint32_t* out = (uint32_t*)base;          // front 16 KB = 4096 dwords
    #pragma unroll
    for (int rr = 0; rr < 16; ++rr) {
        const int od = rr * 256 + threadIdx.x;        // coalesced writes
        const int chunk = od >> 8, i = chunk >> 3, sk = chunk & 7;
        const int H = (od >> 7) & 1, m5 = (od >> 2) & 31, d = od & 3;
        const int m = 32 * i + m5, k = 8 * sk + 4 * H + d;
        const float2 a = right ? st[m * 65 + k] : st[k * 65 + m];
        out[od] = pk2(a.x, a.y);              // lo = w0, hi = w1
    }
}

__device__ __forceinline__ void dma16(const void* gp, void* lp) {
    __builtin_amdgcn_global_load_lds(
        (const __attribute__((address_space(1))) uint32_t*)gp,
        (__attribute__((address_space(3))) uint32_t*)lp, 16, 0, 0);
}

// ---------------------------------------------------------------------------
// Stage 1: per (side, segment-of-32, batch) build the 64x64 segment product
// via MFMA with K=128 per site (x-combine folded into the contraction).
// 512 blocks x 4 waves (2 blocks/CU); wave = one batch; 4-slot shared DMA
// ring, prefetch depth 2, vmcnt(8)+s_barrier (proven cadence).
// Counter-driven rewrite (VALUBusy 49%): B-fragments for ALL sk are
// pre-extracted from acc BEFORE the MFMA cluster, which then chains directly
// into acc with a persistent zero C at sk=0.  Eliminates the per-site
// nacc-zero-init and acc<-nacc copy (~128-256 VALU cyc/site).  x-scaling via
// v_pk_mul_f32 (64 pk_mul instead of 128 v_mul).  Bit-identical math:
// same IEEE products, same pk2 truncation, same MFMA summation order.
// ---------------------------------------------------------------------------
__global__ __launch_bounds__(256, 2) void stage1_kernel(
        const float* __restrict__ x, float* __restrict__ wl, float* __restrict__ wr) {
    const int bid  = blockIdx.x;          // 0..511
    const int side = bid >> 8;
    const int seg  = (bid >> 4) & 15;
    const int bq   = bid & 15;
    const int wave = threadIdx.x >> 6;
    const int lane = threadIdx.x & 63;
    const int b    = bq * 4 + wave;
    const int m5   = lane & 31;
    const int H    = lane >> 5;

    __shared__ __align__(16) char ring[4][PACK_BYTES];   // 64 KB
    __shared__ float2 xs[4][SEGLEN];

    char* wbuf = (char*)(side ? wr : wl);

    if (lane < SEGLEN) {
        const float2* xp = ((const float2*)x) + (size_t)b * 1024 + (side ? NSITE : 0);
        const int sg = seg * SEGLEN + (side ? SEGLEN - 1 - lane : lane);
        xs[wave][lane] = xp[sg];
    }

    auto siteAddr = [&](int t) -> const char* {
        const int sg = seg * SEGLEN + (side ? SEGLEN - 1 - t : t);
        return wbuf + (size_t)sg * SLAB_BYTES;
    };

    #pragma unroll
    for (int t0 = 0; t0 < 2; ++t0) {
        const char* sb = siteAddr(t0);
        #pragma unroll
        for (int c = 0; c < 4; ++c) {
            const int ch = wave * 4 + c;
            dma16(sb + ch * 1024 + lane * 16, ring[t0] + ch * 1024);
        }
    }

    // acc := Identity (C/D layout: row=(q&3)+8(q>>2)+4H, col=32j+m5)
    f32x16 acc[2][2];
    #pragma unroll
    for (int i = 0; i < 2; ++i)
        #pragma unroll
        for (int j = 0; j < 2; ++j)
            #pragma unroll
            for (int q = 0; q < 16; ++q) {
                const int row = (q & 3) + 8 * (q >> 2) + 4 * H;
                acc[i][j][q] = (i == j && row == m5) ? 1.f : 0.f;
            }

    // persistent zero C-operand (lives across the whole K-loop)
    f32x16 zf;
    #pragma unroll
    for (int q = 0; q < 16; ++q) zf[q] = 0.f;

    union BU { bf16x8 v; uint32_t w[4]; };

    for (int t = 0; t < SEGLEN; ++t) {
        int t2 = t + 2; if (t2 > SEGLEN - 1) t2 = SEGLEN - 1;   // clamped dummy keeps cadence
        {
            const char* sb = siteAddr(t2);
            char* lb = ring[(t + 2) & 3];
            #pragma unroll
            for (int c = 0; c < 4; ++c) {
                const int ch = wave * 4 + c;
                dma16(sb + ch * 1024 + lane * 16, lb + ch * 1024);
            }
        }
        asm volatile("s_waitcnt vmcnt(8)" ::: "memory");
        asm volatile("s_barrier" ::: "memory");

        const char* rb = ring[t & 3];
        const float2 xv = xs[wave][t];
        const float2 xx = make_float2(xv.x, xv.x);
        const float2 xy = make_float2(xv.y, xv.y);

        // ---- pre-extract ALL B-fragments from acc (reads complete before
        //      any acc write below; SSA dataflow enforces the order) ----
        BU bfa[8][2];                              // 64 dwords, static-indexed
        #pragma unroll
        for (int sk = 0; sk < 8; ++sk) {
            const int mi = sk >> 2, qb = 4 * (sk & 3);
            #pragma unroll
            for (int j = 0; j < 2; ++j)
                #pragma unroll
                for (int dp = 0; dp < 2; ++dp) {
                    const float2 v01 = make_float2(acc[mi][j][qb + 2 * dp],
                                                   acc[mi][j][qb + 2 * dp + 1]);
                    const float2 pa = pkmul2(xx, v01);   // {x0*v0, x0*v1}
                    const float2 pb = pkmul2(xy, v01);   // {x1*v0, x1*v1}
                    bfa[sk][j].w[2 * dp + 0] = pk2(pa.x, pb.x);  // kap even: x0
                    bfa[sk][j].w[2 * dp + 1] = pk2(pa.y, pb.y);  // kap odd : x1
                }
        }

        // ---- MFMA cluster: chain directly into acc, C=zf at sk==0 ----
        __builtin_amdgcn_s_setprio(1);
        #pragma unroll
        for (int sk = 0; sk < 8; ++sk) {
            #pragma unroll
            for (int i = 0; i < 2; ++i) {
                union { bf16x8 v; uint4 u; } a;
                a.u = *(const uint4*)(rb + (i * 8 + sk) * 1024 + lane * 16);
                #pragma unroll
                for (int j = 0; j < 2; ++j)
                    acc[i][j] = __builtin_amdgcn_mfma_f32_32x32x16_bf16(
                        a.v, bfa[sk][j].v, (sk == 0) ? zf : acc[i][j], 0, 0, 0);
            }
        }
        __builtin_amdgcn_s_setprio(0);
    }

    // write P (final T, bf16, uint16 index c*64+r) into slab back-halves
    {
        const int p = b * NSEG + seg;                    // 0..1023 per side
        char* pdst = wbuf + (size_t)(p >> 1) * SLAB_BYTES + PACK_BYTES + (p & 1) * 8192;
        #pragma unroll
        for (int i = 0; i < 2; ++i)
            #pragma unroll
            for (int j = 0; j < 2; ++j) {
                const int c = 32 * j + m5;
                #pragma unroll
                for (int Q = 0; Q < 4; ++Q) {
                    const int r0 = 32 * i + 8 * Q + 4 * H;
                    uint2 val;
                    val.x = pk2(acc[i][j][4 * Q + 0], acc[i][j][4 * Q + 1]);
                    val.y = pk2(acc[i][j][4 * Q + 2], acc[i][j][4 * Q + 3]);
                    *(uint2*)(pdst + c * 128 + r0 * 2) = val;
                }
            }
    }
    asm volatile("s_waitcnt vmcnt(0)" ::: "memory");   // drain DMA before endpgm
}

// ---------------------------------------------------------------------------
// Stage 2: fold 16 segment matrices into the boundary vector per chain.
// 128 blocks x 256 threads; 4 waves split the c-sum, LDS tree reduce.
// Register prefetch of next segment's P + raw s_barrier with manual
// lgkmcnt(0) only (no vmcnt drain) so the prefetch loads stay in flight
// across BOTH barriers; they are waited only at the pv<-nv copy.
// ---------------------------------------------------------------------------
__global__ __launch_bounds__(256) void stage2_kernel(
        const float* __restrict__ wl, const float* __restrict__ wr,
        float* __restrict__ vbuf) {
    const int chain = blockIdx.x;        // 0..127
    const int side  = chain >> 6, b = chain & 63;
    const int tid   = threadIdx.x, r = tid & 63, cg = tid >> 6;
    const char* wbuf = (const char*)(side ? wr : wl);

    __shared__ float vsh[DD];
    __shared__ float part[4][DD];
    if (tid < DD) vsh[tid] = (tid == 0) ? 1.f : 0.f;

    auto Pseg = [&](int gi) -> const uint16_t* {
        const int g = side ? (NSEG - 1 - gi) : gi;
        const int p = b * NSEG + g;
        return (const uint16_t*)(wbuf
            + (size_t)(p >> 1) * SLAB_BYTES + PACK_BYTES + (p & 1) * 8192);
    };

    float pv[16];
    {
        const uint16_t* P = Pseg(0);
        #pragma unroll
        for (int cc = 0; cc < 16; ++cc)
            pv[cc] = __uint_as_float(((uint32_t)P[(cg * 16 + cc) * 64 + r]) << 16);
    }
    __syncthreads();

    for (int gi = 0; gi < NSEG; ++gi) {
        float nv[16];
        const bool more = (gi + 1 < NSEG);
        if (more) {
            const uint16_t* Pn = Pseg(gi + 1);          // issue early; waited at copy
            #pragma unroll
            for (int cc = 0; cc < 16; ++cc)
                nv[cc] = __uint_as_float(((uint32_t)Pn[(cg * 16 + cc) * 64 + r]) << 16);
        }
        float acc = 0.f;
        #pragma unroll
        for (int cc = 0; cc < 16; ++cc)
            acc = fmaf(vsh[cg * 16 + cc], pv[cc], acc);
        part[cg][r] = acc;
        asm volatile("s_waitcnt lgkmcnt(0)" ::: "memory");
        __builtin_amdgcn_s_barrier();
        if (tid < DD) vsh[tid] = part[0][tid] + part[1][tid] + part[2][tid] + part[3][tid];
        asm volatile("s_waitcnt lgkmcnt(0)" ::: "memory");
        __builtin_amdgcn_s_barrier();
        if (more) {
            #pragma unroll
            for (int cc = 0; cc < 16; ++cc) pv[cc] = nv[cc];
        }
    }
    if (tid < DD) vbuf[chain * DD + tid] = vsh[tid];
}

// out[b,o] = sum_{l,r} vL[b,l] * core[o,l,r] * wR[b,r]
__global__ __launch_bounds__(64) void finalize_kernel(
        const float* __restrict__ core,
        const float* __restrict__ vbuf,
        float* __restrict__ out) {
    const int b    = blockIdx.x;
    const int lane = threadIdx.x;
    __shared__ float vls[DD];
    vls[lane] = vbuf[b * DD + lane];
    const float wr = vbuf[(NB + b) * DD + lane];
    __syncthreads();
    for (int o = 0; o < NO; ++o) {
        float acc = 0.f;
        #pragma unroll 8
        for (int l = 0; l < DD; ++l)
            acc += vls[l] * core[(o * DD + l) * DD + lane];
        acc *= wr;
        #pragma unroll
        for (int off = 32; off > 0; off >>= 1)
            acc += __shfl_xor(acc, off, 64);
        if (lane == 0) out[b * NO + o] = acc;
    }
}

extern "C" void kernel_launch(void* const* d_in, const int* in_sizes, int n_in,
                              void* d_out, int out_size, void* d_ws, size_t ws_size,
                              hipStream_t stream) {
    const float* x    = (const float*)d_in[0];   // [64][1024][2]
    float*       wl   = (float*)d_in[1];         // [512][64][64][2] -> packed + P scratch
    const float* core = (const float*)d_in[2];   // [10][64][64]
    float*       wr   = (float*)d_in[3];         // [512][64][64][2] -> packed + P scratch
    float* vbuf = (float*)d_ws;                  // 32 KB

    pack_kernel<<<2 * NSITE, 256, 0, stream>>>(wl, wr);
    stage1_kernel<<<512, 256, 0, stream>>>(x, wl, wr);
    stage2_kernel<<<2 * NB, 256, 0, stream>>>(wl, wr, vbuf);
    finalize_kernel<<<NB, DD, 0, stream>>>(core, vbuf, (float*)d_out);
}